// Round 4
// baseline (525.755 us; speedup 1.0000x reference)
//
#include <hip/hip_runtime.h>
#include <hip/hip_bf16.h>
#include <cstddef>
#include <cstdint>

#define NBLK(n, b) (((n) + (b) - 1) / (b))

typedef __attribute__((ext_vector_type(8))) short short8;
typedef __attribute__((ext_vector_type(4))) float f32x4;

__device__ inline unsigned short f2bf(float f) {
  union { float f; unsigned u; } v; v.f = f;
  unsigned u = v.u;
  u += 0x7FFFu + ((u >> 16) & 1u);  // RNE
  return (unsigned short)(u >> 16);
}
__device__ inline float bflo(unsigned u) { union { unsigned u; float f; } v; v.u = u << 16; return v.f; }
__device__ inline float bfhi(unsigned u) { union { unsigned u; float f; } v; v.u = u & 0xFFFF0000u; return v.f; }

// ---------------- fused setup: cast x, zero deg, prep W1..W3, detect dtype ----------------

__device__ inline void prep_w_dev(const float* __restrict__ Wl, const float* __restrict__ Wr,
                                  unsigned short* __restrict__ Wb, int b) {
  int i = b * 256 + threadIdx.x;
  int nrow = i >> 8, k = i & 255;
  float v = (k < 128) ? Wr[nrow * 128 + k] : Wl[nrow * 128 + (k - 128)];
  Wb[i] = f2bf(v);
}

__global__ void k_setup(const float* __restrict__ x, unsigned* __restrict__ xb, int N,
                        int* __restrict__ deg,
                        const float* __restrict__ W1l, const float* __restrict__ W1r, unsigned short* __restrict__ Wb1,
                        const float* __restrict__ W2l, const float* __restrict__ W2r, unsigned short* __restrict__ Wb2,
                        const float* __restrict__ W3l, const float* __restrict__ W3r, unsigned short* __restrict__ Wb3,
                        const unsigned* __restrict__ edges, int* __restrict__ flag) {
  int b = blockIdx.x;
  int gCast = (N * 64 + 255) >> 8;
  int gZero = (N + 255) >> 8;
  if (b < gCast) {
    int i = b * 256 + threadIdx.x;
    if (i < N * 64) {
      float2 v = *(const float2*)(x + (size_t)i * 2);
      xb[i] = (unsigned)f2bf(v.x) | ((unsigned)f2bf(v.y) << 16);
    }
    return;
  }
  b -= gCast;
  if (b < gZero) {
    int i = b * 256 + threadIdx.x;
    if (i < N) deg[i] = 0;
    return;
  }
  b -= gZero;
  if (b < 128) { prep_w_dev(W1l, W1r, Wb1, b); return; }
  b -= 128;
  if (b < 128) { prep_w_dev(W2l, W2r, Wb2, b); return; }
  b -= 128;
  if (b < 64) { prep_w_dev(W3l, W3r, Wb3, b); return; }
  b -= 64;
  if (b == 0 && threadIdx.x == 0) {
    int is64 = 1;
#pragma unroll
    for (int i = 0; i < 16; ++i)
      if (edges[2 * i + 1] != 0u) is64 = 0;
    *flag = is64;
  }
}

// ---------------- CSR build ----------------
// histogram + per-edge rank; 4 edges/thread, 4 independent atomics in flight.
__global__ void k_hist_rank(const void* __restrict__ edges, const int* __restrict__ flag,
                            int* __restrict__ deg, int* __restrict__ rank, int E) {
  int t = blockIdx.x * blockDim.x + threadIdx.x;
  int e0 = t * 4;
  if (e0 >= E) return;
  bool full = (e0 + 4 <= E) && ((E & 3) == 0);
  if (full) {
    int d0, d1, d2, d3;
    if (*flag) {
      const long long* p = (const long long*)edges + E + e0;
      longlong2 a = *(const longlong2*)p;
      longlong2 b = *(const longlong2*)(p + 2);
      d0 = (int)a.x; d1 = (int)a.y; d2 = (int)b.x; d3 = (int)b.y;
    } else {
      int4 a = *(const int4*)((const int*)edges + E + e0);
      d0 = a.x; d1 = a.y; d2 = a.z; d3 = a.w;
    }
    int r0 = atomicAdd(&deg[d0], 1);
    int r1 = atomicAdd(&deg[d1], 1);
    int r2 = atomicAdd(&deg[d2], 1);
    int r3 = atomicAdd(&deg[d3], 1);
    *(int4*)(rank + e0) = make_int4(r0, r1, r2, r3);
  } else {
    for (int i = 0; i < 4 && e0 + i < E; ++i) {
      int d;
      if (*flag) d = (int)((const long long*)edges)[(size_t)E + e0 + i];
      else       d = ((const int*)edges)[(size_t)E + e0 + i];
      rank[e0 + i] = atomicAdd(&deg[d], 1);
    }
  }
}

// Block-level exclusive scan: 256 threads x 4 items = 1024 elems/block.
__global__ void k_scan1(const int* __restrict__ deg, int* __restrict__ rowptr,
                        int* __restrict__ partials, int n) {
  __shared__ int sd[256];
  int t = threadIdx.x;
  int base = blockIdx.x * 1024 + t * 4;
  int v[4];
  int sum = 0;
#pragma unroll
  for (int i = 0; i < 4; ++i) {
    int idx = base + i;
    v[i] = (idx < n) ? deg[idx] : 0;
    sum += v[i];
  }
  sd[t] = sum;
  __syncthreads();
  for (int off = 1; off < 256; off <<= 1) {
    int xv = (t >= off) ? sd[t - off] : 0;
    __syncthreads();
    sd[t] += xv;
    __syncthreads();
  }
  int run = sd[t] - sum;
#pragma unroll
  for (int i = 0; i < 4; ++i) {
    int idx = base + i;
    if (idx < n) rowptr[idx] = run;
    run += v[i];
  }
  if (t == 0) partials[blockIdx.x] = sd[255];
}

__global__ void k_scan2(int* __restrict__ partials, int nb) {
  __shared__ int sd[256];
  int t = threadIdx.x;
  int v = (t < nb) ? partials[t] : 0;
  sd[t] = v;
  __syncthreads();
  for (int off = 1; off < 256; off <<= 1) {
    int xv = (t >= off) ? sd[t - off] : 0;
    __syncthreads();
    sd[t] += xv;
    __syncthreads();
  }
  if (t < nb) partials[t] = sd[t] - v;
}

__global__ void k_scan_add(int* __restrict__ rowptr, const int* __restrict__ partials, int n, int E) {
  int i = blockIdx.x * blockDim.x + threadIdx.x;
  if (i < n) rowptr[i] += partials[i >> 10];
  if (blockIdx.x == 0 && threadIdx.x == 0) rowptr[n] = E;
}

// atomic-free fill; 4 edges/thread, independent gathers, nontemporal scatter.
__global__ void k_fill2(const void* __restrict__ edges, const int* __restrict__ flag,
                        const int* __restrict__ rowptr, const int* __restrict__ rank,
                        int* __restrict__ srcSorted, int E) {
  int t = blockIdx.x * blockDim.x + threadIdx.x;
  int e0 = t * 4;
  if (e0 >= E) return;
  bool full = (e0 + 4 <= E) && ((E & 3) == 0);
  if (full) {
    int s0, s1, s2, s3, d0, d1, d2, d3;
    if (*flag) {
      const long long* ps = (const long long*)edges + e0;
      const long long* pd = (const long long*)edges + E + e0;
      longlong2 a = *(const longlong2*)ps;
      longlong2 b = *(const longlong2*)(ps + 2);
      longlong2 c = *(const longlong2*)pd;
      longlong2 d = *(const longlong2*)(pd + 2);
      s0 = (int)a.x; s1 = (int)a.y; s2 = (int)b.x; s3 = (int)b.y;
      d0 = (int)c.x; d1 = (int)c.y; d2 = (int)d.x; d3 = (int)d.y;
    } else {
      int4 a = *(const int4*)((const int*)edges + e0);
      int4 b = *(const int4*)((const int*)edges + E + e0);
      s0 = a.x; s1 = a.y; s2 = a.z; s3 = a.w;
      d0 = b.x; d1 = b.y; d2 = b.z; d3 = b.w;
    }
    int4 rk = *(const int4*)(rank + e0);
    int p0 = rowptr[d0] + rk.x;
    int p1 = rowptr[d1] + rk.y;
    int p2 = rowptr[d2] + rk.z;
    int p3 = rowptr[d3] + rk.w;
    __builtin_nontemporal_store(s0, &srcSorted[p0]);
    __builtin_nontemporal_store(s1, &srcSorted[p1]);
    __builtin_nontemporal_store(s2, &srcSorted[p2]);
    __builtin_nontemporal_store(s3, &srcSorted[p3]);
  } else {
    for (int i = 0; i < 4 && e0 + i < E; ++i) {
      int s, d;
      if (*flag) {
        const long long* p = (const long long*)edges;
        s = (int)p[e0 + i];
        d = (int)p[(size_t)E + e0 + i];
      } else {
        const int* p = (const int*)edges;
        s = p[e0 + i];
        d = p[(size_t)E + e0 + i];
      }
      srcSorted[rowptr[d] + rank[e0 + i]] = s;
    }
  }
}

// ---------------- aggregation: mean over in-neighbors (bf16 in/out, fp32 acc) ----------------
// One wave per node. Lane = (eg in [0,4)) x (sub in [0,16)): 4 edge rows loaded
// per 16B/lane instruction (1 KB/wave in flight), main loop unrolled x2.
__global__ void k_aggregate(const unsigned* __restrict__ in, const int* __restrict__ rowptr,
                            const int* __restrict__ srcs, unsigned* __restrict__ mean, int n) {
  int lane = threadIdx.x & 63;
  int w = threadIdx.x >> 6;
  int node = blockIdx.x * 4 + w;
  if (node >= n) return;
  int r0 = rowptr[node], r1 = rowptr[node + 1];
  int sub = lane & 15;  // channel group: 8 channels (16 B)
  int eg = lane >> 4;   // edge slot 0..3
  float acc[8];
#pragma unroll
  for (int k = 0; k < 8; ++k) acc[k] = 0.f;

  for (int base = r0; base < r1; base += 64) {
    int e = base + lane;
    int sv = (e < r1) ? srcs[e] : 0;
    int cnt = min(64, r1 - base);
    int j = 0;
    for (; j + 8 <= cnt; j += 8) {
      int s0 = __shfl(sv, j + eg);
      int s1 = __shfl(sv, j + 4 + eg);
      uint4 u0 = *(const uint4*)(in + (size_t)s0 * 64 + sub * 4);
      uint4 u1 = *(const uint4*)(in + (size_t)s1 * 64 + sub * 4);
      acc[0] += bflo(u0.x); acc[1] += bfhi(u0.x);
      acc[2] += bflo(u0.y); acc[3] += bfhi(u0.y);
      acc[4] += bflo(u0.z); acc[5] += bfhi(u0.z);
      acc[6] += bflo(u0.w); acc[7] += bfhi(u0.w);
      acc[0] += bflo(u1.x); acc[1] += bfhi(u1.x);
      acc[2] += bflo(u1.y); acc[3] += bfhi(u1.y);
      acc[4] += bflo(u1.z); acc[5] += bfhi(u1.z);
      acc[6] += bflo(u1.w); acc[7] += bfhi(u1.w);
    }
    for (; j < cnt; j += 4) {
      int jj = j + eg;
      int s = __shfl(sv, jj);
      if (jj < cnt) {
        uint4 u = *(const uint4*)(in + (size_t)s * 64 + sub * 4);
        acc[0] += bflo(u.x); acc[1] += bfhi(u.x);
        acc[2] += bflo(u.y); acc[3] += bfhi(u.y);
        acc[4] += bflo(u.z); acc[5] += bfhi(u.z);
        acc[6] += bflo(u.w); acc[7] += bfhi(u.w);
      }
    }
  }

#pragma unroll
  for (int k = 0; k < 8; ++k) {
    acc[k] += __shfl_down(acc[k], 32);
    acc[k] += __shfl_down(acc[k], 16);
  }
  if (eg == 0) {
    float sc = 1.0f / (float)max(r1 - r0, 1);
    uint4 o;
    o.x = (unsigned)f2bf(acc[0] * sc) | ((unsigned)f2bf(acc[1] * sc) << 16);
    o.y = (unsigned)f2bf(acc[2] * sc) | ((unsigned)f2bf(acc[3] * sc) << 16);
    o.z = (unsigned)f2bf(acc[4] * sc) | ((unsigned)f2bf(acc[5] * sc) << 16);
    o.w = (unsigned)f2bf(acc[6] * sc) | ((unsigned)f2bf(acc[7] * sc) << 16);
    *(uint4*)(mean + (size_t)node * 64 + sub * 4) = o;
  }
}

// ---------------- MFMA GEMM: out = self@Wr.T + mean@Wl.T + b  (K=256 concat) ----------------
template <int H, bool RELU, bool BF16OUT>
__global__ __launch_bounds__(256) void k_gemm(
    const unsigned short* __restrict__ selfB, const unsigned short* __restrict__ meanB,
    const unsigned short* __restrict__ Wb, const float* __restrict__ bias,
    void* __restrict__ outp, int n) {
  constexpr int TN = H / 32;  // col tiles per wave
  int lane = threadIdx.x & 63;
  int w = threadIdx.x >> 6;
  int wr = w & 1, wc = w >> 1;
  int nodeBase = blockIdx.x * 128 + wr * 64;
  int colBase = wc * (H / 2);
  int l15 = lane & 15, quad = lane >> 4;

  f32x4 acc[4][TN];
#pragma unroll
  for (int t = 0; t < 4; ++t)
#pragma unroll
    for (int j = 0; j < TN; ++j) acc[t][j] = (f32x4){0.f, 0.f, 0.f, 0.f};

#pragma unroll
  for (int c = 0; c < 8; ++c) {
    const unsigned short* A = (c < 4) ? selfB : meanB;
    int ko = (c & 3) * 32 + quad * 8;
    short8 af[4], bfr[TN];
#pragma unroll
    for (int t = 0; t < 4; ++t) {
      int row = nodeBase + t * 16 + l15;
      row = min(row, n - 1);
      af[t] = *(const short8*)(A + (size_t)row * 128 + ko);
    }
#pragma unroll
    for (int j = 0; j < TN; ++j) {
      int cn = colBase + j * 16 + l15;
      bfr[j] = *(const short8*)(Wb + (size_t)cn * 256 + c * 32 + quad * 8);
    }
#pragma unroll
    for (int t = 0; t < 4; ++t)
#pragma unroll
      for (int j = 0; j < TN; ++j)
        acc[t][j] = __builtin_amdgcn_mfma_f32_16x16x32_bf16(af[t], bfr[j], acc[t][j], 0, 0, 0);
  }

#pragma unroll
  for (int j = 0; j < TN; ++j) {
    int col = colBase + j * 16 + l15;
    float bv = bias[col];
#pragma unroll
    for (int t = 0; t < 4; ++t) {
#pragma unroll
      for (int r = 0; r < 4; ++r) {
        int row = nodeBase + t * 16 + quad * 4 + r;
        if (row < n) {
          float v = acc[t][j][r] + bv;
          if (RELU) v = fmaxf(v, 0.f);
          if (BF16OUT) ((unsigned short*)outp)[(size_t)row * H + col] = f2bf(v);
          else ((float*)outp)[(size_t)row * H + col] = v;
        }
      }
    }
  }
}

// ---------------- launch ----------------

extern "C" void kernel_launch(void* const* d_in, const int* in_sizes, int n_in,
                              void* d_out, int out_size, void* d_ws, size_t ws_size,
                              hipStream_t stream) {
  (void)n_in; (void)out_size; (void)ws_size;
  const float* x = (const float*)d_in[0];
  const void* edges = d_in[1];
  const float* W1l = (const float*)d_in[2];
  const float* W1r = (const float*)d_in[3];
  const float* b1 = (const float*)d_in[4];
  const float* W2l = (const float*)d_in[5];
  const float* W2r = (const float*)d_in[6];
  const float* b2 = (const float*)d_in[7];
  const float* W3l = (const float*)d_in[8];
  const float* W3r = (const float*)d_in[9];
  const float* b3 = (const float*)d_in[10];
  float* out = (float*)d_out;

  const int N = in_sizes[0] / 128;
  const int E = in_sizes[1] / 2;

  char* ws = (char*)d_ws;
  size_t off = 0;
  auto alloc = [&](size_t bytes) -> char* {
    char* p = ws + off;
    off = (off + bytes + 255) & ~(size_t)255;
    return p;
  };
  int* flag = (int*)alloc(4);
  int* deg = (int*)alloc((size_t)N * 4);
  int* rowptr = (int*)alloc((size_t)(N + 1) * 4);
  int* rank = (int*)alloc((size_t)E * 4);
  int* partials = (int*)alloc(4096);
  int* srcSorted = (int*)alloc((size_t)E * 4);
  unsigned short* xb = (unsigned short*)alloc((size_t)N * 128 * 2);
  unsigned short* mean = (unsigned short*)alloc((size_t)N * 128 * 2);
  unsigned short* h1 = (unsigned short*)alloc((size_t)N * 128 * 2);
  unsigned short* h2 = (unsigned short*)alloc((size_t)N * 128 * 2);
  unsigned short* Wb1 = (unsigned short*)alloc(128 * 256 * 2);
  unsigned short* Wb2 = (unsigned short*)alloc(128 * 256 * 2);
  unsigned short* Wb3 = (unsigned short*)alloc(64 * 256 * 2);

  int nb1 = (N + 1023) / 1024;
  int gSetup = NBLK(N * 64, 256) + NBLK(N, 256) + 128 + 128 + 64 + 1;

  k_setup<<<gSetup, 256, 0, stream>>>(x, (unsigned*)xb, N, deg,
                                      W1l, W1r, Wb1, W2l, W2r, Wb2, W3l, W3r, Wb3,
                                      (const unsigned*)edges, flag);
  k_hist_rank<<<NBLK(E, 1024), 256, 0, stream>>>(edges, flag, deg, rank, E);
  k_scan1<<<nb1, 256, 0, stream>>>(deg, rowptr, partials, N);
  k_scan2<<<1, 256, 0, stream>>>(partials, nb1);
  k_scan_add<<<NBLK(N, 256), 256, 0, stream>>>(rowptr, partials, N, E);
  k_fill2<<<NBLK(E, 1024), 256, 0, stream>>>(edges, flag, rowptr, rank, srcSorted, E);

  int gAgg = NBLK(N, 4);
  int gGemm = NBLK(N, 128);

  // layer 1
  k_aggregate<<<gAgg, 256, 0, stream>>>((const unsigned*)xb, rowptr, srcSorted, (unsigned*)mean, N);
  k_gemm<128, true, true><<<gGemm, 256, 0, stream>>>(xb, mean, Wb1, b1, h1, N);
  // layer 2
  k_aggregate<<<gAgg, 256, 0, stream>>>((const unsigned*)h1, rowptr, srcSorted, (unsigned*)mean, N);
  k_gemm<128, true, true><<<gGemm, 256, 0, stream>>>(h1, mean, Wb2, b2, h2, N);
  // layer 3
  k_aggregate<<<gAgg, 256, 0, stream>>>((const unsigned*)h2, rowptr, srcSorted, (unsigned*)mean, N);
  k_gemm<64, false, false><<<gGemm, 256, 0, stream>>>(h2, mean, Wb3, b3, out, N);
}

// Round 5
// 472.479 us; speedup vs baseline: 1.1128x; 1.1128x over previous
//
#include <hip/hip_runtime.h>
#include <hip/hip_bf16.h>
#include <cstddef>
#include <cstdint>

#define NBLK(n, b) (((n) + (b) - 1) / (b))

typedef __attribute__((ext_vector_type(8))) short short8;
typedef __attribute__((ext_vector_type(4))) float f32x4;

__device__ inline unsigned short f2bf(float f) {
  union { float f; unsigned u; } v; v.f = f;
  unsigned u = v.u;
  u += 0x7FFFu + ((u >> 16) & 1u);  // RNE
  return (unsigned short)(u >> 16);
}
__device__ inline float bflo(unsigned u) { union { unsigned u; float f; } v; v.u = u << 16; return v.f; }
__device__ inline float bfhi(unsigned u) { union { unsigned u; float f; } v; v.u = u & 0xFFFF0000u; return v.f; }

// CSR bucket sort parameters: buckets of 512 nodes; node ids < 2^17 (N=100K).
// key = src | (localDst << 17) fits u32 (17 + 9 = 26 bits).
#define BSHIFT 9
#define BSIZE 512

// ---------------- fused setup: cast x, prep W1..W3, zero bucketCnt, detect dtype ----------------

__device__ inline void prep_w_dev(const float* __restrict__ Wl, const float* __restrict__ Wr,
                                  unsigned short* __restrict__ Wb, int b) {
  int i = b * 256 + threadIdx.x;
  int nrow = i >> 8, k = i & 255;
  float v = (k < 128) ? Wr[nrow * 128 + k] : Wl[nrow * 128 + (k - 128)];
  Wb[i] = f2bf(v);
}

__global__ void k_setup(const float* __restrict__ x, unsigned* __restrict__ xb, int N,
                        int* __restrict__ bucketCnt, int NB,
                        const float* __restrict__ W1l, const float* __restrict__ W1r, unsigned short* __restrict__ Wb1,
                        const float* __restrict__ W2l, const float* __restrict__ W2r, unsigned short* __restrict__ Wb2,
                        const float* __restrict__ W3l, const float* __restrict__ W3r, unsigned short* __restrict__ Wb3,
                        const unsigned* __restrict__ edges, int* __restrict__ flag) {
  int b = blockIdx.x;
  int gCast = (N * 64 + 255) >> 8;
  if (b < gCast) {
    int i = b * 256 + threadIdx.x;
    if (i < N * 64) {
      float2 v = *(const float2*)(x + (size_t)i * 2);
      xb[i] = (unsigned)f2bf(v.x) | ((unsigned)f2bf(v.y) << 16);
    }
    return;
  }
  b -= gCast;
  if (b < 128) { prep_w_dev(W1l, W1r, Wb1, b); return; }
  b -= 128;
  if (b < 128) { prep_w_dev(W2l, W2r, Wb2, b); return; }
  b -= 128;
  if (b < 64) { prep_w_dev(W3l, W3r, Wb3, b); return; }
  b -= 64;
  if (b == 0) {
    for (int i = threadIdx.x; i < NB; i += 256) bucketCnt[i] = 0;
    if (threadIdx.x == 0) {
      int is64 = 1;
#pragma unroll
      for (int i = 0; i < 16; ++i)
        if (edges[2 * i + 1] != 0u) is64 = 0;
      *flag = is64;
    }
  }
}

// ---------------- CSR build: two-level bucket sort, no per-edge global atomics ----------------

// Pass 1a: coarse histogram of dst>>9 via LDS; one global atomic per bucket per block.
__global__ __launch_bounds__(256) void k_bhist(const void* __restrict__ edges, const int* __restrict__ flag,
                                               int* __restrict__ bucketCnt, int E, int NB) {
  __shared__ int h[1024];
  for (int i = threadIdx.x; i < NB; i += 256) h[i] = 0;
  __syncthreads();
  int base_e = blockIdx.x * 4096;
  bool is64 = (*flag) != 0;
#pragma unroll
  for (int k = 0; k < 16; ++k) {
    int e = base_e + k * 256 + threadIdx.x;
    if (e < E) {
      int d;
      if (is64) d = (int)((const long long*)edges)[(size_t)E + e];
      else      d = ((const int*)edges)[(size_t)E + e];
      atomicAdd(&h[d >> BSHIFT], 1);
    }
  }
  __syncthreads();
  for (int i = threadIdx.x; i < NB; i += 256) {
    int c = h[i];
    if (c) atomicAdd(&bucketCnt[i], c);
  }
}

// Pass 1b: exclusive scan of bucket counts (single block; NB <= 1024).
__global__ void k_bscan(const int* __restrict__ bucketCnt, int* __restrict__ bucketBase,
                        int* __restrict__ bucketCursor, int NB, int E) {
  __shared__ int sd[256];
  int t = threadIdx.x;
  int base = t * 4;
  int v[4];
  int sum = 0;
#pragma unroll
  for (int i = 0; i < 4; ++i) {
    int idx = base + i;
    v[i] = (idx < NB) ? bucketCnt[idx] : 0;
    sum += v[i];
  }
  sd[t] = sum;
  __syncthreads();
  for (int off = 1; off < 256; off <<= 1) {
    int xv = (t >= off) ? sd[t - off] : 0;
    __syncthreads();
    sd[t] += xv;
    __syncthreads();
  }
  int run = sd[t] - sum;
#pragma unroll
  for (int i = 0; i < 4; ++i) {
    int idx = base + i;
    if (idx < NB) { bucketBase[idx] = run; bucketCursor[idx] = run; }
    run += v[i];
  }
  if (t == 0) bucketBase[NB] = E;
}

// Pass 1c: scatter packed keys into bucket regions. Per-block LDS hist ->
// one reservation atomic per bucket per block -> LDS-rank placement.
__global__ __launch_bounds__(256) void k_bscatter(const void* __restrict__ edges, const int* __restrict__ flag,
                                                  int* __restrict__ bucketCursor, unsigned* __restrict__ bucketed,
                                                  int E, int NB) {
  __shared__ int h[1024];
  __shared__ int base[1024];
  for (int i = threadIdx.x; i < NB; i += 256) h[i] = 0;
  __syncthreads();
  int base_e = blockIdx.x * 4096;
  bool is64 = (*flag) != 0;
  unsigned key[16];
  int bkt[16];
#pragma unroll
  for (int k = 0; k < 16; ++k) {
    int e = base_e + k * 256 + threadIdx.x;
    bkt[k] = -1;
    if (e < E) {
      int s, d;
      if (is64) {
        s = (int)((const long long*)edges)[e];
        d = (int)((const long long*)edges)[(size_t)E + e];
      } else {
        s = ((const int*)edges)[e];
        d = ((const int*)edges)[(size_t)E + e];
      }
      bkt[k] = d >> BSHIFT;
      key[k] = (unsigned)s | ((unsigned)(d & (BSIZE - 1)) << 17);
      atomicAdd(&h[bkt[k]], 1);
    }
  }
  __syncthreads();
  for (int i = threadIdx.x; i < NB; i += 256) {
    int c = h[i];
    base[i] = c ? atomicAdd(&bucketCursor[i], c) : 0;
    h[i] = 0;
  }
  __syncthreads();
#pragma unroll
  for (int k = 0; k < 16; ++k) {
    if (bkt[k] >= 0) {
      int r = atomicAdd(&h[bkt[k]], 1);
      bucketed[base[bkt[k]] + r] = key[k];
    }
  }
}

// Pass 2: one block per bucket -> local 512-node CSR (rowptr + srcSorted).
__global__ __launch_bounds__(256) void k_csr(const unsigned* __restrict__ bucketed,
                                             const int* __restrict__ bucketBase,
                                             int* __restrict__ rowptr, int* __restrict__ srcSorted,
                                             int N, int E, int NB) {
  __shared__ int h[512];
  __shared__ int excl[512];
  __shared__ int sd[256];
  int b = blockIdx.x;
  int t = threadIdx.x;
  int nodeBase = b << BSHIFT;
  int nNode = min(BSIZE, N - nodeBase);
  int s0 = bucketBase[b], s1 = bucketBase[b + 1];
  int cnt = s1 - s0;
  h[t * 2] = 0; h[t * 2 + 1] = 0;
  __syncthreads();
  for (int i = t; i < cnt; i += 256) {
    int ld = bucketed[s0 + i] >> 17;
    atomicAdd(&h[ld], 1);
  }
  __syncthreads();
  int a0 = h[t * 2], a1 = h[t * 2 + 1];
  int s = a0 + a1;
  sd[t] = s;
  __syncthreads();
  for (int off = 1; off < 256; off <<= 1) {
    int xv = (t >= off) ? sd[t - off] : 0;
    __syncthreads();
    sd[t] += xv;
    __syncthreads();
  }
  int run = sd[t] - s;
  excl[t * 2] = run;
  excl[t * 2 + 1] = run + a0;
  if (t * 2 < nNode) rowptr[nodeBase + t * 2] = s0 + run;
  if (t * 2 + 1 < nNode) rowptr[nodeBase + t * 2 + 1] = s0 + run + a0;
  if (b == NB - 1 && t == 0) rowptr[N] = E;
  h[t * 2] = 0; h[t * 2 + 1] = 0;
  __syncthreads();
  for (int i = t; i < cnt; i += 256) {
    unsigned u = bucketed[s0 + i];
    int ld = u >> 17;
    int r = atomicAdd(&h[ld], 1);
    srcSorted[s0 + excl[ld] + r] = (int)(u & 0x1FFFFu);
  }
}

// ---------------- aggregation: mean over in-neighbors (bf16 in/out, fp32 acc) ----------------
// One wave per node. Lane = (eg in [0,4)) x (sub in [0,16)): 4 edge rows loaded
// per 16B/lane instruction (1 KB/wave in flight), main loop unrolled x2.
__global__ void k_aggregate(const unsigned* __restrict__ in, const int* __restrict__ rowptr,
                            const int* __restrict__ srcs, unsigned* __restrict__ mean, int n) {
  int lane = threadIdx.x & 63;
  int w = threadIdx.x >> 6;
  int node = blockIdx.x * 4 + w;
  if (node >= n) return;
  int r0 = rowptr[node], r1 = rowptr[node + 1];
  int sub = lane & 15;  // channel group: 8 channels (16 B)
  int eg = lane >> 4;   // edge slot 0..3
  float acc[8];
#pragma unroll
  for (int k = 0; k < 8; ++k) acc[k] = 0.f;

  for (int base = r0; base < r1; base += 64) {
    int e = base + lane;
    int sv = (e < r1) ? srcs[e] : 0;
    int cnt = min(64, r1 - base);
    int j = 0;
    for (; j + 8 <= cnt; j += 8) {
      int s0 = __shfl(sv, j + eg);
      int s1 = __shfl(sv, j + 4 + eg);
      uint4 u0 = *(const uint4*)(in + (size_t)s0 * 64 + sub * 4);
      uint4 u1 = *(const uint4*)(in + (size_t)s1 * 64 + sub * 4);
      acc[0] += bflo(u0.x); acc[1] += bfhi(u0.x);
      acc[2] += bflo(u0.y); acc[3] += bfhi(u0.y);
      acc[4] += bflo(u0.z); acc[5] += bfhi(u0.z);
      acc[6] += bflo(u0.w); acc[7] += bfhi(u0.w);
      acc[0] += bflo(u1.x); acc[1] += bfhi(u1.x);
      acc[2] += bflo(u1.y); acc[3] += bfhi(u1.y);
      acc[4] += bflo(u1.z); acc[5] += bfhi(u1.z);
      acc[6] += bflo(u1.w); acc[7] += bfhi(u1.w);
    }
    for (; j < cnt; j += 4) {
      int jj = j + eg;
      int s = __shfl(sv, jj);
      if (jj < cnt) {
        uint4 u = *(const uint4*)(in + (size_t)s * 64 + sub * 4);
        acc[0] += bflo(u.x); acc[1] += bfhi(u.x);
        acc[2] += bflo(u.y); acc[3] += bfhi(u.y);
        acc[4] += bflo(u.z); acc[5] += bfhi(u.z);
        acc[6] += bflo(u.w); acc[7] += bfhi(u.w);
      }
    }
  }

#pragma unroll
  for (int k = 0; k < 8; ++k) {
    acc[k] += __shfl_down(acc[k], 32);
    acc[k] += __shfl_down(acc[k], 16);
  }
  if (eg == 0) {
    float sc = 1.0f / (float)max(r1 - r0, 1);
    uint4 o;
    o.x = (unsigned)f2bf(acc[0] * sc) | ((unsigned)f2bf(acc[1] * sc) << 16);
    o.y = (unsigned)f2bf(acc[2] * sc) | ((unsigned)f2bf(acc[3] * sc) << 16);
    o.z = (unsigned)f2bf(acc[4] * sc) | ((unsigned)f2bf(acc[5] * sc) << 16);
    o.w = (unsigned)f2bf(acc[6] * sc) | ((unsigned)f2bf(acc[7] * sc) << 16);
    *(uint4*)(mean + (size_t)node * 64 + sub * 4) = o;
  }
}

// ---------------- MFMA GEMM: out = self@Wr.T + mean@Wl.T + b  (K=256 concat) ----------------
template <int H, bool RELU, bool BF16OUT>
__global__ __launch_bounds__(256) void k_gemm(
    const unsigned short* __restrict__ selfB, const unsigned short* __restrict__ meanB,
    const unsigned short* __restrict__ Wb, const float* __restrict__ bias,
    void* __restrict__ outp, int n) {
  constexpr int TN = H / 32;  // col tiles per wave
  int lane = threadIdx.x & 63;
  int w = threadIdx.x >> 6;
  int wr = w & 1, wc = w >> 1;
  int nodeBase = blockIdx.x * 128 + wr * 64;
  int colBase = wc * (H / 2);
  int l15 = lane & 15, quad = lane >> 4;

  f32x4 acc[4][TN];
#pragma unroll
  for (int t = 0; t < 4; ++t)
#pragma unroll
    for (int j = 0; j < TN; ++j) acc[t][j] = (f32x4){0.f, 0.f, 0.f, 0.f};

#pragma unroll
  for (int c = 0; c < 8; ++c) {
    const unsigned short* A = (c < 4) ? selfB : meanB;
    int ko = (c & 3) * 32 + quad * 8;
    short8 af[4], bfr[TN];
#pragma unroll
    for (int t = 0; t < 4; ++t) {
      int row = nodeBase + t * 16 + l15;
      row = min(row, n - 1);
      af[t] = *(const short8*)(A + (size_t)row * 128 + ko);
    }
#pragma unroll
    for (int j = 0; j < TN; ++j) {
      int cn = colBase + j * 16 + l15;
      bfr[j] = *(const short8*)(Wb + (size_t)cn * 256 + c * 32 + quad * 8);
    }
#pragma unroll
    for (int t = 0; t < 4; ++t)
#pragma unroll
      for (int j = 0; j < TN; ++j)
        acc[t][j] = __builtin_amdgcn_mfma_f32_16x16x32_bf16(af[t], bfr[j], acc[t][j], 0, 0, 0);
  }

#pragma unroll
  for (int j = 0; j < TN; ++j) {
    int col = colBase + j * 16 + l15;
    float bv = bias[col];
#pragma unroll
    for (int t = 0; t < 4; ++t) {
#pragma unroll
      for (int r = 0; r < 4; ++r) {
        int row = nodeBase + t * 16 + quad * 4 + r;
        if (row < n) {
          float v = acc[t][j][r] + bv;
          if (RELU) v = fmaxf(v, 0.f);
          if (BF16OUT) ((unsigned short*)outp)[(size_t)row * H + col] = f2bf(v);
          else ((float*)outp)[(size_t)row * H + col] = v;
        }
      }
    }
  }
}

// ---------------- launch ----------------

extern "C" void kernel_launch(void* const* d_in, const int* in_sizes, int n_in,
                              void* d_out, int out_size, void* d_ws, size_t ws_size,
                              hipStream_t stream) {
  (void)n_in; (void)out_size; (void)ws_size;
  const float* x = (const float*)d_in[0];
  const void* edges = d_in[1];
  const float* W1l = (const float*)d_in[2];
  const float* W1r = (const float*)d_in[3];
  const float* b1 = (const float*)d_in[4];
  const float* W2l = (const float*)d_in[5];
  const float* W2r = (const float*)d_in[6];
  const float* b2 = (const float*)d_in[7];
  const float* W3l = (const float*)d_in[8];
  const float* W3r = (const float*)d_in[9];
  const float* b3 = (const float*)d_in[10];
  float* out = (float*)d_out;

  const int N = in_sizes[0] / 128;
  const int E = in_sizes[1] / 2;
  const int NB = (N + BSIZE - 1) >> BSHIFT;

  char* ws = (char*)d_ws;
  size_t off = 0;
  auto alloc = [&](size_t bytes) -> char* {
    char* p = ws + off;
    off = (off + bytes + 255) & ~(size_t)255;
    return p;
  };
  int* flag = (int*)alloc(4);
  int* bucketCnt = (int*)alloc((size_t)NB * 4);
  int* bucketBase = (int*)alloc((size_t)(NB + 1) * 4);
  int* bucketCursor = (int*)alloc((size_t)NB * 4);
  unsigned* bucketed = (unsigned*)alloc((size_t)E * 4);
  int* rowptr = (int*)alloc((size_t)(N + 1) * 4);
  int* srcSorted = (int*)alloc((size_t)E * 4);
  unsigned short* xb = (unsigned short*)alloc((size_t)N * 128 * 2);
  unsigned short* mean = (unsigned short*)alloc((size_t)N * 128 * 2);
  unsigned short* h1 = (unsigned short*)alloc((size_t)N * 128 * 2);
  unsigned short* h2 = (unsigned short*)alloc((size_t)N * 128 * 2);
  unsigned short* Wb1 = (unsigned short*)alloc(128 * 256 * 2);
  unsigned short* Wb2 = (unsigned short*)alloc(128 * 256 * 2);
  unsigned short* Wb3 = (unsigned short*)alloc(64 * 256 * 2);

  int gSetup = NBLK(N * 64, 256) + 128 + 128 + 64 + 1;
  int gE = NBLK(E, 4096);

  k_setup<<<gSetup, 256, 0, stream>>>(x, (unsigned*)xb, N, bucketCnt, NB,
                                      W1l, W1r, Wb1, W2l, W2r, Wb2, W3l, W3r, Wb3,
                                      (const unsigned*)edges, flag);
  k_bhist<<<gE, 256, 0, stream>>>(edges, flag, bucketCnt, E, NB);
  k_bscan<<<1, 256, 0, stream>>>(bucketCnt, bucketBase, bucketCursor, NB, E);
  k_bscatter<<<gE, 256, 0, stream>>>(edges, flag, bucketCursor, bucketed, E, NB);
  k_csr<<<NB, 256, 0, stream>>>(bucketed, bucketBase, rowptr, srcSorted, N, E, NB);

  int gAgg = NBLK(N, 4);
  int gGemm = NBLK(N, 128);

  // layer 1
  k_aggregate<<<gAgg, 256, 0, stream>>>((const unsigned*)xb, rowptr, srcSorted, (unsigned*)mean, N);
  k_gemm<128, true, true><<<gGemm, 256, 0, stream>>>(xb, mean, Wb1, b1, h1, N);
  // layer 2
  k_aggregate<<<gAgg, 256, 0, stream>>>((const unsigned*)h1, rowptr, srcSorted, (unsigned*)mean, N);
  k_gemm<128, true, true><<<gGemm, 256, 0, stream>>>(h1, mean, Wb2, b2, h2, N);
  // layer 3
  k_aggregate<<<gAgg, 256, 0, stream>>>((const unsigned*)h2, rowptr, srcSorted, (unsigned*)mean, N);
  k_gemm<64, false, false><<<gGemm, 256, 0, stream>>>(h2, mean, Wb3, b3, out, N);
}